// Round 2
// baseline (772.401 us; speedup 1.0000x reference)
//
#include <hip/hip_runtime.h>
#include <math.h>

// Gating: logits = x @ W^T + b (D=1024, E=16); softmax; top-2 scatter.
// Outputs concatenated in d_out: gated^T [16,65536], weights^T [16,65536].
//
// R2 design: split-D across 4 waves per block (lane = token, wave = quarter
// of D). Each lane streams its private 1KB row-slice straight from global
// (8 chunks of 8 x float4 = one 128B line per lane per chunk -> MSHR-merged),
// register double-buffered, NO LDS staging, NO barriers in the main loop.
// 16 waves/CU (4/SIMD) for TLP. Partial logits reduced through a 17KB LDS
// tile with a single barrier; every wave computes softmax/top-2 redundantly
// and stores a 4-expert slice (coalesced).

constexpr int D     = 1024;
constexpr int NE    = 16;
constexpr int NTOK  = 8 * 8192;        // 65536 tokens
constexpr int TPB   = 256;             // 4 waves
constexpr int TOKS  = 64;              // tokens per block (= lanes)
constexpr int PARTS = 4;               // D split across the 4 waves
constexpr int PDIM  = D / PARTS;       // 256 dims per thread
constexpr int CF4   = 8;               // float4 per chunk = 128B line per lane
constexpr int NCH   = PDIM / (CF4 * 4); // 8 chunks
constexpr int LSTR  = NE * PARTS + 4;  // 68 floats: 16B-aligned rows, breaks pow2 banks

__global__ __launch_bounds__(TPB) void gating_kernel(
    const float* __restrict__ x,
    const float* __restrict__ W,
    const float* __restrict__ bias,
    float* __restrict__ out)
{
    __shared__ float lds[TOKS * LSTR];   // 64*68*4 = 17408 B
    const int t    = threadIdx.x;
    const int lane = t & 63;             // token within block
    const int wv   = t >> 6;             // which quarter of D
    const long tok = (long)blockIdx.x * TOKS + lane;

    const float4* __restrict__ xr4 = (const float4*)(x + tok * D + (long)wv * PDIM);
    const float*  __restrict__ Wp  = W + wv * PDIM;

    float acc[NE];
    #pragma unroll
    for (int e = 0; e < NE; ++e) acc[e] = 0.0f;

    float4 pf0[CF4], pf1[CF4];
    #pragma unroll
    for (int j = 0; j < CF4; ++j) pf0[j] = xr4[j];     // chunk 0 in flight

    #pragma unroll 1
    for (int c = 0; c < NCH; c += 2) {
        // issue chunk c+1 loads, compute chunk c from pf0
        #pragma unroll
        for (int j = 0; j < CF4; ++j) pf1[j] = xr4[(c + 1) * CF4 + j];
        #pragma unroll
        for (int j = 0; j < CF4; ++j) {
            const float4 xv = pf0[j];
            #pragma unroll
            for (int e = 0; e < NE; ++e) {
                const float4 w4 = *(const float4*)(Wp + e * D + (c * CF4 + j) * 4);
                acc[e] = fmaf(xv.x, w4.x, acc[e]);
                acc[e] = fmaf(xv.y, w4.y, acc[e]);
                acc[e] = fmaf(xv.z, w4.z, acc[e]);
                acc[e] = fmaf(xv.w, w4.w, acc[e]);
            }
        }
        // issue chunk c+2 loads, compute chunk c+1 from pf1
        if (c + 2 < NCH) {
            #pragma unroll
            for (int j = 0; j < CF4; ++j) pf0[j] = xr4[(c + 2) * CF4 + j];
        }
        #pragma unroll
        for (int j = 0; j < CF4; ++j) {
            const float4 xv = pf1[j];
            #pragma unroll
            for (int e = 0; e < NE; ++e) {
                const float4 w4 = *(const float4*)(Wp + e * D + ((c + 1) * CF4 + j) * 4);
                acc[e] = fmaf(xv.x, w4.x, acc[e]);
                acc[e] = fmaf(xv.y, w4.y, acc[e]);
                acc[e] = fmaf(xv.z, w4.z, acc[e]);
                acc[e] = fmaf(xv.w, w4.w, acc[e]);
            }
        }
    }

    // ---- cross-wave reduction of the 4 D-slices via LDS (single barrier) ----
    #pragma unroll
    for (int e = 0; e < NE; ++e)
        lds[lane * LSTR + e * 4 + wv] = acc[e];
    __syncthreads();

    // all 4 waves redundantly compute the epilogue for their lane's token
    float logits[NE];
    float m = -INFINITY;
    #pragma unroll
    for (int e = 0; e < NE; ++e) {
        const float4 p = *(const float4*)&lds[lane * LSTR + e * 4];
        logits[e] = p.x + p.y + p.z + p.w + bias[e];
        m = fmaxf(m, logits[e]);
    }
    float w[NE];
    float s = 0.0f;
    #pragma unroll
    for (int e = 0; e < NE; ++e) {
        w[e] = __expf(logits[e] - m);
        s += w[e];
    }
    const float inv = 1.0f / s;
    #pragma unroll
    for (int e = 0; e < NE; ++e) w[e] *= inv;

    // top-2 (ties -> lowest index, matching lax.top_k); validated in R1
    float b1 = -1.0f; int i1 = 0;
    float b2 = -1.0f; int i2 = 0;
    #pragma unroll
    for (int e = 0; e < NE; ++e) {
        if (w[e] > b1)      { b2 = b1; i2 = i1; b1 = w[e]; i1 = e; }
        else if (w[e] > b2) { b2 = w[e]; i2 = e; }
    }

    // wave wv stores its 4-expert slice for both outputs (coalesced per e)
    float* __restrict__ out0 = out;                    // gated^T  [16][65536]
    float* __restrict__ out1 = out + (long)NE * NTOK;  // weights^T[16][65536]
    #pragma unroll
    for (int i = 0; i < NE / PARTS; ++i) {
        const int e = wv * (NE / PARTS) + i;
        const float g = (e == i1) ? b1 : ((e == i2) ? b2 : 0.0f);
        out0[(long)e * NTOK + tok] = g;
        out1[(long)e * NTOK + tok] = w[e];
    }
}

extern "C" void kernel_launch(void* const* d_in, const int* in_sizes, int n_in,
                              void* d_out, int out_size, void* d_ws, size_t ws_size,
                              hipStream_t stream) {
    const float* x = (const float*)d_in[0];
    const float* W = (const float*)d_in[1];
    const float* b = (const float*)d_in[2];
    float* out = (float*)d_out;

    dim3 grid(NTOK / TOKS);   // 1024 blocks -> 4 blocks/CU, 16 waves/CU
    dim3 block(TPB);
    gating_kernel<<<grid, block, 0, stream>>>(x, W, b, out);
}

// Round 3
// 453.436 us; speedup vs baseline: 1.7034x; 1.7034x over previous
//
#include <hip/hip_runtime.h>
#include <math.h>

// Gating: logits = x @ W^T + b (D=1024, E=16); softmax; top-2 scatter.
// Outputs concatenated in d_out: gated^T [16,65536], weights^T [16,65536].
//
// R3: R2's split-D (4 waves per 64 tokens, barrier-free main loop) with the
// register pressure fixed. R2 spilled (VGPR=256, ~750MB scratch traffic).
// Changes: single 8xfloat4 prefetch buffer, expert-OUTER inner loop (only 8
// W float4 live), __launch_bounds__(256,4) capping VGPRs at 128 so 4
// waves/SIMD (16/CU) hide load latency via TLP instead of double-buffering.
// Per chunk: 512 fma = 1024 SIMD-cyc x 4 waves = 4096 cyc >> ~930 cyc load
// latency -> stalls covered. Memory-bound target: 264 MB -> ~42 us floor.

constexpr int D     = 1024;
constexpr int NE    = 16;
constexpr int NTOK  = 8 * 8192;          // 65536 tokens
constexpr int TPB   = 256;               // 4 waves
constexpr int TOKS  = 64;                // tokens per block (= lanes)
constexpr int PARTS = 4;                 // D split across the 4 waves
constexpr int PDIM  = D / PARTS;         // 256 dims per thread
constexpr int CF4   = 8;                 // float4 per chunk = 128B/lane line
constexpr int NCH   = PDIM / (CF4 * 4);  // 8 chunks
constexpr int LSTR  = NE * PARTS + 4;    // 68 floats: 16B-aligned rows

__global__ __launch_bounds__(TPB, 4) void gating_kernel(
    const float* __restrict__ x,
    const float* __restrict__ W,
    const float* __restrict__ bias,
    float* __restrict__ out)
{
    __shared__ float lds[TOKS * LSTR];   // 17408 B
    const int t    = threadIdx.x;
    const int lane = t & 63;             // token within block
    const int wv   = t >> 6;             // which quarter of D
    const long tok = (long)blockIdx.x * TOKS + lane;

    const float4* __restrict__ xr4 = (const float4*)(x + tok * D + (long)wv * PDIM);
    const float4* __restrict__ Wp4 = (const float4*)(W + wv * PDIM);

    float acc[NE];
    #pragma unroll
    for (int e = 0; e < NE; ++e) acc[e] = 0.0f;

    #pragma unroll 1
    for (int c = 0; c < NCH; ++c) {
        // one 128B line per lane, 8 back-to-back float4 loads (MSHR-merged)
        float4 pf[CF4];
        #pragma unroll
        for (int j = 0; j < CF4; ++j) pf[j] = xr4[c * CF4 + j];

        // expert-outer: only CF4 W-values live at once; x chunk reused 16x
        #pragma unroll
        for (int e = 0; e < NE; ++e) {
            #pragma unroll
            for (int j = 0; j < CF4; ++j) {
                const float4 w4 = Wp4[e * (D / 4) + c * CF4 + j];  // uniform, L1/L2-hot
                acc[e] = fmaf(pf[j].x, w4.x, acc[e]);
                acc[e] = fmaf(pf[j].y, w4.y, acc[e]);
                acc[e] = fmaf(pf[j].z, w4.z, acc[e]);
                acc[e] = fmaf(pf[j].w, w4.w, acc[e]);
            }
        }
    }

    // ---- cross-wave reduction of the 4 D-slices via LDS (single barrier) ----
    #pragma unroll
    for (int e = 0; e < NE; ++e)
        lds[lane * LSTR + e * 4 + wv] = acc[e];
    __syncthreads();

    // all 4 waves redundantly compute the epilogue for their lane's token
    float logits[NE];
    float m = -INFINITY;
    #pragma unroll
    for (int e = 0; e < NE; ++e) {
        const float4 p = *(const float4*)&lds[lane * LSTR + e * 4];
        logits[e] = p.x + p.y + p.z + p.w + bias[e];
        m = fmaxf(m, logits[e]);
    }
    float w[NE];
    float s = 0.0f;
    #pragma unroll
    for (int e = 0; e < NE; ++e) {
        w[e] = __expf(logits[e] - m);
        s += w[e];
    }
    const float inv = 1.0f / s;
    #pragma unroll
    for (int e = 0; e < NE; ++e) w[e] *= inv;

    // top-2 (ties -> lowest index, matching lax.top_k); validated R1/R2
    float b1 = -1.0f; int i1 = 0;
    float b2 = -1.0f; int i2 = 0;
    #pragma unroll
    for (int e = 0; e < NE; ++e) {
        if (w[e] > b1)      { b2 = b1; i2 = i1; b1 = w[e]; i1 = e; }
        else if (w[e] > b2) { b2 = w[e]; i2 = e; }
    }

    // wave wv stores its 4-expert slice for both outputs (coalesced per e)
    float* __restrict__ out0 = out;                    // gated^T  [16][65536]
    float* __restrict__ out1 = out + (long)NE * NTOK;  // weights^T[16][65536]
    #pragma unroll
    for (int i = 0; i < NE / PARTS; ++i) {
        const int e = wv * (NE / PARTS) + i;
        const float g = (e == i1) ? b1 : ((e == i2) ? b2 : 0.0f);
        out0[(long)e * NTOK + tok] = g;
        out1[(long)e * NTOK + tok] = w[e];
    }
}

extern "C" void kernel_launch(void* const* d_in, const int* in_sizes, int n_in,
                              void* d_out, int out_size, void* d_ws, size_t ws_size,
                              hipStream_t stream) {
    const float* x = (const float*)d_in[0];
    const float* W = (const float*)d_in[1];
    const float* b = (const float*)d_in[2];
    float* out = (float*)d_out;

    dim3 grid(NTOK / TOKS);   // 1024 blocks -> 4 blocks/CU, 16 waves/CU
    dim3 block(TPB);
    gating_kernel<<<grid, block, 0, stream>>>(x, W, b, out);
}

// Round 4
// 390.721 us; speedup vs baseline: 1.9769x; 1.1605x over previous
//
#include <hip/hip_runtime.h>
#include <math.h>

// Gating: logits = x @ W^T + b (D=1024, E=16); softmax; top-2 scatter.
// Outputs concatenated in d_out: gated^T [16,65536], weights^T [16,65536].
//
// R4: R3 + W on the SCALAR pipe. R3's 3x VALU inflation and VMEM flood came
// from per-lane W loads (wv divergent -> global_load_dwordx4 x 16384/CU).
// W's address is wave-uniform: readfirstlane(wv*PDIM) marks it uniform ->
// s_load (SMEM pipe, SGPR operands into v_fmac). With W out of the VGPR
// budget, the 2-chunk x double-buffer returns (~95 live VGPRs < 128, no R2
// spill). Memory-bound target: ~264 MB -> ~42 us floor at 6.3 TB/s.

constexpr int D     = 1024;
constexpr int NE    = 16;
constexpr int NTOK  = 8 * 8192;          // 65536 tokens
constexpr int TPB   = 256;               // 4 waves
constexpr int TOKS  = 64;                // tokens per block (= lanes)
constexpr int PARTS = 4;                 // D split across the 4 waves
constexpr int PDIM  = D / PARTS;         // 256 dims per thread
constexpr int CF4   = 8;                 // float4 per chunk = 128B/lane line
constexpr int NCH   = PDIM / (CF4 * 4);  // 8 chunks
constexpr int LSTR  = NE * PARTS + 4;    // 68 floats: 16B-aligned rows

__global__ __launch_bounds__(TPB, 4) void gating_kernel(
    const float* __restrict__ x,
    const float* __restrict__ W,
    const float* __restrict__ bias,
    float* __restrict__ out)
{
    __shared__ float lds[TOKS * LSTR];   // 17408 B
    const int t    = threadIdx.x;
    const int lane = t & 63;             // token within block
    const int wv   = t >> 6;             // which quarter of D
    const long tok = (long)blockIdx.x * TOKS + lane;

    const float4* __restrict__ xr4 = (const float4*)(x + tok * D + (long)wv * PDIM);
    // Wave-uniform W base: readfirstlane makes it uniform to the compiler's
    // divergence analysis -> const __restrict__ loads promote to s_load.
    const int wOff = __builtin_amdgcn_readfirstlane(wv * PDIM);
    const float* __restrict__ Wu = W + wOff;

    float acc[NE];
    #pragma unroll
    for (int e = 0; e < NE; ++e) acc[e] = 0.0f;

    float4 pf0[CF4], pf1[CF4];
    #pragma unroll
    for (int j = 0; j < CF4; ++j) pf0[j] = xr4[j];     // chunk 0 in flight

    #pragma unroll
    for (int c = 0; c < NCH; c += 2) {
        // issue chunk c+1 x-loads, compute chunk c from pf0 (W via SMEM)
        #pragma unroll
        for (int j = 0; j < CF4; ++j) pf1[j] = xr4[(c + 1) * CF4 + j];
        #pragma unroll
        for (int e = 0; e < NE; ++e) {
            #pragma unroll
            for (int j = 0; j < CF4; ++j) {
                const float4 w4 = *(const float4*)(Wu + e * D + (c * CF4 + j) * 4);
                acc[e] = fmaf(pf0[j].x, w4.x, acc[e]);
                acc[e] = fmaf(pf0[j].y, w4.y, acc[e]);
                acc[e] = fmaf(pf0[j].z, w4.z, acc[e]);
                acc[e] = fmaf(pf0[j].w, w4.w, acc[e]);
            }
        }
        // issue chunk c+2 x-loads, compute chunk c+1 from pf1
        if (c + 2 < NCH) {
            #pragma unroll
            for (int j = 0; j < CF4; ++j) pf0[j] = xr4[(c + 2) * CF4 + j];
        }
        #pragma unroll
        for (int e = 0; e < NE; ++e) {
            #pragma unroll
            for (int j = 0; j < CF4; ++j) {
                const float4 w4 = *(const float4*)(Wu + e * D + ((c + 1) * CF4 + j) * 4);
                acc[e] = fmaf(pf1[j].x, w4.x, acc[e]);
                acc[e] = fmaf(pf1[j].y, w4.y, acc[e]);
                acc[e] = fmaf(pf1[j].z, w4.z, acc[e]);
                acc[e] = fmaf(pf1[j].w, w4.w, acc[e]);
            }
        }
    }

    // ---- cross-wave reduction of the 4 D-slices via LDS (single barrier) ----
    #pragma unroll
    for (int e = 0; e < NE; ++e)
        lds[lane * LSTR + e * 4 + wv] = acc[e];
    __syncthreads();

    // all 4 waves redundantly compute the epilogue for their lane's token
    float logits[NE];
    float m = -INFINITY;
    #pragma unroll
    for (int e = 0; e < NE; ++e) {
        const float4 p = *(const float4*)&lds[lane * LSTR + e * 4];
        logits[e] = p.x + p.y + p.z + p.w + bias[e];
        m = fmaxf(m, logits[e]);
    }
    float w[NE];
    float s = 0.0f;
    #pragma unroll
    for (int e = 0; e < NE; ++e) {
        w[e] = __expf(logits[e] - m);
        s += w[e];
    }
    const float inv = 1.0f / s;
    #pragma unroll
    for (int e = 0; e < NE; ++e) w[e] *= inv;

    // top-2 (ties -> lowest index, matching lax.top_k); validated R1-R3
    float b1 = -1.0f; int i1 = 0;
    float b2 = -1.0f; int i2 = 0;
    #pragma unroll
    for (int e = 0; e < NE; ++e) {
        if (w[e] > b1)      { b2 = b1; i2 = i1; b1 = w[e]; i1 = e; }
        else if (w[e] > b2) { b2 = w[e]; i2 = e; }
    }

    // wave wv stores its 4-expert slice for both outputs (coalesced per e)
    float* __restrict__ out0 = out;                    // gated^T  [16][65536]
    float* __restrict__ out1 = out + (long)NE * NTOK;  // weights^T[16][65536]
    #pragma unroll
    for (int i = 0; i < NE / PARTS; ++i) {
        const int e = wv * (NE / PARTS) + i;
        const float g = (e == i1) ? b1 : ((e == i2) ? b2 : 0.0f);
        out0[(long)e * NTOK + tok] = g;
        out1[(long)e * NTOK + tok] = w[e];
    }
}

extern "C" void kernel_launch(void* const* d_in, const int* in_sizes, int n_in,
                              void* d_out, int out_size, void* d_ws, size_t ws_size,
                              hipStream_t stream) {
    const float* x = (const float*)d_in[0];
    const float* W = (const float*)d_in[1];
    const float* b = (const float*)d_in[2];
    float* out = (float*)d_out;

    dim3 grid(NTOK / TOKS);   // 1024 blocks -> 4 blocks/CU, 16 waves/CU
    dim3 block(TPB);
    gating_kernel<<<grid, block, 0, stream>>>(x, W, b, out);
}